// Round 3
// baseline (1193.950 us; speedup 1.0000x reference)
//
#include <hip/hip_runtime.h>
#include <math.h>

#define NN 100000
#define NE 1600000
#define CC 128
#define C3 384
#define SCAN_B 256
#define SCAN_NB ((NN + SCAN_B - 1) / SCAN_B)  // 391 (also = coarse bucket count)
#define NCHUNK ((NN + 31) / 32)               // 3125 dst chunks of 32 nodes
#define GEN_BLOCKS 1024                       // 4 blocks/CU x 256 CU, all resident

typedef __attribute__((ext_vector_type(4))) float f4;
typedef __attribute__((ext_vector_type(8))) short s8;

__device__ __forceinline__ float sigmoidf_(float x) { return 1.0f / (1.0f + __expf(-x)); }
__device__ __forceinline__ float tanhf_(float x) { return 2.0f / (1.0f + __expf(-2.0f * x)) - 1.0f; }

__device__ __forceinline__ short f2bf(float x) {
    unsigned u = __float_as_uint(x);
    unsigned r = (u + 0x7fffu + ((u >> 16) & 1u)) >> 16;
    return (short)r;
}
__device__ __forceinline__ float bf2f(short s) {
    return __uint_as_float(((unsigned)(unsigned short)s) << 16);
}

// ---- edge dtype: int64 => all odd int32 words zero. Computed per-block (L1-cached). ----
__device__ __forceinline__ int detect_flag(const int* e32) {
    int allz = 1;
#pragma unroll
    for (int i = 0; i < 32; i++)
        if (e32[2 * i + 1] != 0) allz = 0;
    return allz;
}

__device__ __forceinline__ int edge_val(const void* edges, int f, long long idx) {
    return f ? (int)((const long long*)edges)[idx] : ((const int*)edges)[idx];
}

__global__ void k_count(const void* __restrict__ edges, int* __restrict__ counts) {
    __shared__ int sf;
    if (threadIdx.x == 0) sf = detect_flag((const int*)edges);
    __syncthreads();
    int f = sf;
    int e = blockIdx.x * blockDim.x + threadIdx.x;
    if (e < NE) {
        int d = edge_val(edges, f, (long long)NE + e);
        atomicAdd(&counts[d], 1);
    }
}

// ---- multi-block scan ----
__global__ void k_scan1(const int* __restrict__ counts, int* __restrict__ bsum) {
    __shared__ int red[4];
    int t = threadIdx.x;
    int i = blockIdx.x * SCAN_B + t;
    int v = (i < NN) ? counts[i] : 0;
#pragma unroll
    for (int off = 32; off; off >>= 1) v += __shfl_down(v, off);
    if ((t & 63) == 0) red[t >> 6] = v;
    __syncthreads();
    if (t == 0) bsum[blockIdx.x] = red[0] + red[1] + red[2] + red[3];
}

__global__ void k_scan2(const int* __restrict__ bsum, int* __restrict__ boff,
                        int* __restrict__ coarse_cursor) {
    __shared__ int lds[512];
    int t = threadIdx.x;
    int v = (t < SCAN_NB) ? bsum[t] : 0;
    lds[t] = v;
    __syncthreads();
    for (int off = 1; off < 512; off <<= 1) {
        int u = (t >= off) ? lds[t - off] : 0;
        __syncthreads();
        lds[t] += u;
        __syncthreads();
    }
    if (t < SCAN_NB) {
        int ex = lds[t] - v;
        boff[t] = ex;
        coarse_cursor[t] = ex;
    }
}

__global__ void k_scan3(const int* __restrict__ counts, const int* __restrict__ boff,
                        int* __restrict__ rowptr, float* __restrict__ inv_denom) {
    __shared__ int lds[SCAN_B];
    int t = threadIdx.x;
    int i = blockIdx.x * SCAN_B + t;
    int v = (i < NN) ? counts[i] : 0;
    lds[t] = v;
    __syncthreads();
    for (int off = 1; off < SCAN_B; off <<= 1) {
        int u = (t >= off) ? lds[t - off] : 0;
        __syncthreads();
        lds[t] += u;
        __syncthreads();
    }
    if (i < NN) {
        rowptr[i] = boff[blockIdx.x] + lds[t] - v;
        inv_denom[i] = 1.0f / (float)((v > 1) ? v : 1);
    }
    if (i == 0) rowptr[NN] = NE;
}

// ---- CSR build phase 1: partition into coarse-bucket-grouped (src,dst) pairs ----
__global__ __launch_bounds__(1024) void k_part(const void* __restrict__ edges,
                                               int* __restrict__ coarse_cursor,
                                               uint2* __restrict__ tmp) {
    __shared__ int hist[SCAN_NB];
    __shared__ int base[SCAN_NB];
    __shared__ int sf;
    int t = threadIdx.x;
    if (t == 0) sf = detect_flag((const int*)edges);
    long long e0 = (long long)blockIdx.x * 8192;

    for (int c = t; c < SCAN_NB; c += 1024) hist[c] = 0;
    __syncthreads();
    int f = sf;

    int src[8], dst[8];
#pragma unroll
    for (int i = 0; i < 8; i++) {
        long long e = e0 + i * 1024 + t;
        if (e < NE) {
            src[i] = edge_val(edges, f, e);
            dst[i] = edge_val(edges, f, NE + e);
            atomicAdd(&hist[dst[i] >> 8], 1);
        } else {
            dst[i] = -1;
        }
    }
    __syncthreads();
    for (int c = t; c < SCAN_NB; c += 1024) {
        int h = hist[c];
        base[c] = (h > 0) ? atomicAdd(&coarse_cursor[c], h) : 0;
        hist[c] = 0;
    }
    __syncthreads();
#pragma unroll
    for (int i = 0; i < 8; i++) {
        if (dst[i] >= 0) {
            int c = dst[i] >> 8;
            int off = atomicAdd(&hist[c], 1);
            tmp[base[c] + off] = make_uint2((unsigned)src[i], (unsigned)dst[i]);
        }
    }
}

// ---- CSR build phase 2 ----
__global__ void k_fine(const uint2* __restrict__ tmp, const int* __restrict__ rowptr,
                       int* __restrict__ csr_src) {
    __shared__ int cur[256];
    int c = blockIdx.x;
    int t = threadIdx.x;
    int d = c * 256 + t;
    cur[t] = (d <= NN) ? rowptr[d < NN ? d : NN] : NE;
    __syncthreads();
    int start = rowptr[c * 256];
    int endd = (c * 256 + 256 <= NN) ? rowptr[c * 256 + 256] : NE;
    for (int p = start + t; p < endd; p += 256) {
        uint2 pr = tmp[p];
        int slot = atomicAdd(&cur[pr.y & 255], 1);
        csr_src[slot] = (int)pr.x;
    }
}

// ---- R15: sort each CSR row's sources ascending (enables phase-locked src sweep).
// One thread per node, insertion sort in LDS (stride-128 layout -> conflict-free).
// Rows with degree > 64 keep their tail unsorted (correct: still a permutation).
#define DEG_CAP 64
__global__ __launch_bounds__(128) void k_sort(const int* __restrict__ rowptr,
                                              int* __restrict__ csr_src) {
    __shared__ int buf[DEG_CAP * 128];
    int t = threadIdx.x;
    int gid = blockIdx.x * 128 + t;
    if (gid >= NN) return;
    int lo = rowptr[gid], hi = rowptr[gid + 1];
    int deg = hi - lo;
    if (deg > DEG_CAP) deg = DEG_CAP;
    for (int k = 0; k < deg; k++) buf[k * 128 + t] = csr_src[lo + k];
    for (int i = 1; i < deg; i++) {
        int v = buf[i * 128 + t];
        int p = i - 1;
        while (p >= 0 && buf[p * 128 + t] > v) {
            buf[(p + 1) * 128 + t] = buf[p * 128 + t];
            p--;
        }
        buf[(p + 1) * 128 + t] = v;
    }
    for (int k = 0; k < deg; k++) csr_src[lo + k] = buf[k * 128 + t];
}

// ---- weight prep: hi-only B matrices (B bf16-quantized; ah*bl term dropped per R12) ----
__global__ void k_prep(const float* __restrict__ weight, const float* __restrict__ w_ih,
                       const float* __restrict__ w_hh, const float* __restrict__ b_ih,
                       const float* __restrict__ b_hh,
                       short* __restrict__ B1hi, short* __restrict__ B2hi,
                       float* __restrict__ bvec) {
    const int P1 = 3 * C3 * CC;
    int gid = blockIdx.x * blockDim.x + threadIdx.x;
    if (gid < P1) {
        int i = gid / (C3 * CC);
        int rem = gid % (C3 * CC);
        int j = rem / CC;
        int k = rem % CC;
        const float* Wr = weight + i * CC * CC + k * CC;
        const float* ir = w_ih + j * CC;
        float v = 0.f;
#pragma unroll 4
        for (int c = 0; c < CC; c++) v += Wr[c] * ir[c];
        short hi = f2bf(v);
        if (j < 256) B1hi[i * 65536 + j * 256 + k] = hi;
        else B2hi[i * 32768 + (j - 256) * 128 + k] = hi;
    } else if (gid < 2 * P1) {
        int g = gid - P1;
        int i = g / (C3 * CC);
        int rem = g % (C3 * CC);
        int j = rem / CC;
        int k = rem % CC;
        short hi = f2bf(w_hh[j * CC + k]);
        if (j < 256) B1hi[i * 65536 + j * 256 + 128 + k] = hi;
        else B2hi[i * 32768 + (j - 256 + 128) * 128 + k] = hi;
    } else if (gid < 2 * P1 + 512) {
        int j = gid - 2 * P1;
        float v;
        if (j < 256) v = b_ih[j] + b_hh[j];
        else if (j < 384) v = b_ih[j];
        else v = b_hh[j - 128];
        bvec[j] = v;
    }
}

// ---- x -> split-bf16 dense hhi/hlo ----
__global__ void k_cvt(const float* __restrict__ x, unsigned short* __restrict__ hhi,
                      unsigned short* __restrict__ hlo) {
    long long g = ((long long)blockIdx.x * 256 + threadIdx.x) * 8;
    float4 v0 = *(const float4*)(x + g);
    float4 v1 = *(const float4*)(x + g + 4);
    float f[8] = {v0.x, v0.y, v0.z, v0.w, v1.x, v1.y, v1.z, v1.w};
    s8 oh, ol;
#pragma unroll
    for (int q = 0; q < 8; q++) {
        short hi = f2bf(f[q]);
        oh[q] = hi;
        ol[q] = f2bf(f[q] - bf2f(hi));
    }
    *(s8*)(hhi + g) = oh;
    *(s8*)(hlo + g) = ol;
}

// ---- FUSED layer: gather+mean -> split-A x bf16-B MFMA GEMM -> GRU -> h_out / out ----
// R15: persistent-style grid of exactly GEN_BLOCKS=1024 resident blocks; each block
// loops over chunks (blockIdx, +1024, ...). Combined with src-sorted CSR rows, all
// resident blocks sweep src 0->100K in phase each generation -> gather window fits
// per-XCD L2 (latency ~200cy vs ~450cy L3) -> higher MSHR-limited throughput.
// Gather ILP back to 4-deep (R14's 8-deep was a null: compiler capped at 32 VGPR).
__global__ __launch_bounds__(512, 8) void k_fused(
    const unsigned short* __restrict__ hhi_i, const unsigned short* __restrict__ hlo_i,
    unsigned short* __restrict__ hhi_o, unsigned short* __restrict__ hlo_o,
    const int* __restrict__ rowptr, const int* __restrict__ csr_src,
    const float* __restrict__ inv_denom,
    const short* __restrict__ B1hi, const short* __restrict__ B2hi,
    const float* __restrict__ bvec, float* __restrict__ out) {
    __shared__ short Ahi[8192];
    __shared__ short Alo[8192];
    __shared__ float osum[32];
    int t = threadIdx.x;
    int wv = t >> 6;
    int L = t & 63;

    for (int chunk = blockIdx.x; chunk < NCHUNK; chunk += GEN_BLOCKS) {
        long long nb = (long long)chunk * 32;
        __syncthreads();  // protect LDS (Ahi/Alo/osum) reuse across generations
        if (out && t < 32) osum[t] = 0.f;

        // stage h half (cols 128..255): 32 rows x 16 col-groups = 512 s8 copies
        {
            int rr = t >> 4;
            int c = t & 15;
            int c4 = 16 + c;
            long long row = nb + rr;
            int off = (c4 >> 2) * 1024 + (rr >> 4) * 512 + (rr & 15) * 32 + (c4 & 3) * 8;
            long long gsrc = row * CC + c * 8;
            *(s8*)&Ahi[off] = *(const s8*)(hhi_i + gsrc);
            *(s8*)&Alo[off] = *(const s8*)(hlo_i + gsrc);
        }

        // gather + mean into A cols 0..127: quarter-wave per node, 4-edge ILP
        {
            int q = L >> 4;
            int l16 = L & 15;
            int rr = wv * 4 + q;
            long long rowc = nb + rr;
            int lo = rowptr[rowc], hi = rowptr[rowc + 1];
            float acc0[8] = {0, 0, 0, 0, 0, 0, 0, 0};
            float acc1[8] = {0, 0, 0, 0, 0, 0, 0, 0};
            int e = lo;
            for (; e + 3 < hi; e += 4) {
                int s0 = csr_src[e];
                int s1 = csr_src[e + 1];
                int s2 = csr_src[e + 2];
                int s3 = csr_src[e + 3];
                s8 v0 = ((const s8*)(hhi_i + (long long)s0 * CC))[l16];
                s8 v1 = ((const s8*)(hhi_i + (long long)s1 * CC))[l16];
                s8 v2 = ((const s8*)(hhi_i + (long long)s2 * CC))[l16];
                s8 v3 = ((const s8*)(hhi_i + (long long)s3 * CC))[l16];
#pragma unroll
                for (int k = 0; k < 8; k++) {
                    acc0[k] += bf2f(v0[k]) + bf2f(v2[k]);
                    acc1[k] += bf2f(v1[k]) + bf2f(v3[k]);
                }
            }
            for (; e + 1 < hi; e += 2) {
                int s0 = csr_src[e];
                int s1 = csr_src[e + 1];
                s8 v0 = ((const s8*)(hhi_i + (long long)s0 * CC))[l16];
                s8 v1 = ((const s8*)(hhi_i + (long long)s1 * CC))[l16];
#pragma unroll
                for (int k = 0; k < 8; k++) {
                    acc0[k] += bf2f(v0[k]);
                    acc1[k] += bf2f(v1[k]);
                }
            }
            if (e < hi) {
                int s0 = csr_src[e];
                s8 v0 = ((const s8*)(hhi_i + (long long)s0 * CC))[l16];
#pragma unroll
                for (int k = 0; k < 8; k++) acc0[k] += bf2f(v0[k]);
            }
            float inv = inv_denom[rowc];
            s8 vh, vl;
#pragma unroll
            for (int k = 0; k < 8; k++) {
                float f = (acc0[k] + acc1[k]) * inv;
                short hi16 = f2bf(f);
                vh[k] = hi16;
                vl[k] = f2bf(f - bf2f(hi16));
            }
            int off = (l16 >> 2) * 1024 + (rr >> 4) * 512 + (rr & 15) * 32 + (l16 & 3) * 8;
            *(s8*)&Ahi[off] = vh;
            *(s8*)&Alo[off] = vl;
        }
        __syncthreads();

        int lm = L & 15;
        int lq = L >> 4;
        int j = wv * 16 + lm;

        f4 aR[2], aZ[2], aN[2], aH[2];
        {
            float bR = bvec[j], bZ = bvec[128 + j], bN = bvec[256 + j], bH = bvec[384 + j];
#pragma unroll
            for (int ch = 0; ch < 2; ch++) {
                aR[ch] = (f4){bR, bR, bR, bR};
                aZ[ch] = (f4){bZ, bZ, bZ, bZ};
                aN[ch] = (f4){bN, bN, bN, bN};
                aH[ch] = (f4){bH, bH, bH, bH};
            }
        }

#pragma unroll
        for (int ks = 0; ks < 8; ks++) {
            int o1 = ks * 32 + lq * 8;
            s8 bRh = *(const s8*)(B1hi + j * 256 + o1);
            s8 bZh = *(const s8*)(B1hi + (128 + j) * 256 + o1);
            int rowG = (ks < 4) ? j : (128 + j);
            int o2 = (ks & 3) * 32 + lq * 8;
            s8 bGh = *(const s8*)(B2hi + rowG * 128 + o2);
#pragma unroll
            for (int ch = 0; ch < 2; ch++) {
                int aoff = ks * 1024 + ch * 512 + lm * 32 + lq * 8;
                s8 ah = *(const s8*)&Ahi[aoff];
                s8 al = *(const s8*)&Alo[aoff];
                aR[ch] = __builtin_amdgcn_mfma_f32_16x16x32_bf16(ah, bRh, aR[ch], 0, 0, 0);
                aR[ch] = __builtin_amdgcn_mfma_f32_16x16x32_bf16(al, bRh, aR[ch], 0, 0, 0);
                aZ[ch] = __builtin_amdgcn_mfma_f32_16x16x32_bf16(ah, bZh, aZ[ch], 0, 0, 0);
                aZ[ch] = __builtin_amdgcn_mfma_f32_16x16x32_bf16(al, bZh, aZ[ch], 0, 0, 0);
                if (ks < 4) {
                    aN[ch] = __builtin_amdgcn_mfma_f32_16x16x32_bf16(ah, bGh, aN[ch], 0, 0, 0);
                    aN[ch] = __builtin_amdgcn_mfma_f32_16x16x32_bf16(al, bGh, aN[ch], 0, 0, 0);
                } else {
                    aH[ch] = __builtin_amdgcn_mfma_f32_16x16x32_bf16(ah, bGh, aH[ch], 0, 0, 0);
                    aH[ch] = __builtin_amdgcn_mfma_f32_16x16x32_bf16(al, bGh, aH[ch], 0, 0, 0);
                }
            }
        }

        // register-only GRU epilogue
        {
            int c4 = 16 + (j >> 3);
            int obase = (c4 >> 2) * 1024 + (c4 & 3) * 8 + (j & 7);
#pragma unroll
            for (int ch = 0; ch < 2; ch++) {
#pragma unroll
                for (int r = 0; r < 4; r++) {
                    int node = ch * 16 + lq * 4 + r;
                    int off = obase + ch * 512 + (node & 15) * 32;
                    float hp = bf2f(Ahi[off]) + bf2f(Alo[off]);
                    float rg = sigmoidf_(aR[ch][r]);
                    float zg = sigmoidf_(aZ[ch][r]);
                    float nv = tanhf_(aN[ch][r] + rg * aH[ch][r]);
                    float val = (1.f - zg) * nv + zg * hp;
                    long long gnode = nb + node;
                    if (out) {
                        atomicAdd(&osum[(unsigned)node], val);
                    } else {
                        long long gd = gnode * CC + j;
                        short vh = f2bf(val);
                        hhi_o[gd] = (unsigned short)vh;
                        hlo_o[gd] = (unsigned short)f2bf(val - bf2f(vh));
                    }
                }
            }
        }
        if (out) {
            __syncthreads();
            if (t < 32)
                out[nb + t] = tanhf_(osum[t] * (1.0f / 128.0f));
        }
    }
}

extern "C" void kernel_launch(void* const* d_in, const int* in_sizes, int n_in,
                              void* d_out, int out_size, void* d_ws, size_t ws_size,
                              hipStream_t stream) {
    const float* x = (const float*)d_in[0];
    const void* edges = d_in[1];
    const float* weight = (const float*)d_in[2];
    const float* w_ih = (const float*)d_in[3];
    const float* w_hh = (const float*)d_in[4];
    const float* b_ih = (const float*)d_in[5];
    const float* b_hh = (const float*)d_in[6];
    float* out = (float*)d_out;

    char* ws = (char*)d_ws;
    size_t off = 0;
    auto alloc = [&](size_t bytes) -> char* {
        char* p = ws + off;
        off += (bytes + 255) & ~(size_t)255;
        return p;
    };
    // total ws ~122 MB (proven-safe watermark from R4: 162.8 MB)
    int* counts = (int*)alloc((size_t)NN * 4);
    int* rowptr = (int*)alloc((size_t)(NN + 1) * 4);
    int* csr_src = (int*)alloc((size_t)NE * 4);
    float* inv_den = (float*)alloc((size_t)NN * 4);
    int* bsum = (int*)alloc((size_t)SCAN_NB * 4);
    int* boff = (int*)alloc((size_t)SCAN_NB * 4);
    int* coarse_cursor = (int*)alloc((size_t)SCAN_NB * 4);
    uint2* tmp = (uint2*)alloc((size_t)NE * 8);
    short* B1hi = (short*)alloc((size_t)3 * 65536 * 2);
    short* B2hi = (short*)alloc((size_t)3 * 32768 * 2);
    float* bvec = (float*)alloc(512 * 4);
    unsigned short* hhi0 = (unsigned short*)alloc((size_t)NN * CC * 2);
    unsigned short* hlo0 = (unsigned short*)alloc((size_t)NN * CC * 2);
    unsigned short* hhi1 = (unsigned short*)alloc((size_t)NN * CC * 2);
    unsigned short* hlo1 = (unsigned short*)alloc((size_t)NN * CC * 2);

    hipMemsetAsync(counts, 0, (size_t)NN * 4, stream);

    k_count<<<(NE + 255) / 256, 256, 0, stream>>>(edges, counts);
    k_scan1<<<SCAN_NB, SCAN_B, 0, stream>>>(counts, bsum);
    k_scan2<<<1, 512, 0, stream>>>(bsum, boff, coarse_cursor);
    k_scan3<<<SCAN_NB, SCAN_B, 0, stream>>>(counts, boff, rowptr, inv_den);
    k_part<<<(NE + 8191) / 8192, 1024, 0, stream>>>(edges, coarse_cursor, tmp);
    k_fine<<<SCAN_NB, 256, 0, stream>>>(tmp, rowptr, csr_src);
    k_sort<<<(NN + 127) / 128, 128, 0, stream>>>(rowptr, csr_src);
    int prep_threads = 2 * 3 * C3 * CC + 512;
    k_prep<<<(prep_threads + 255) / 256, 256, 0, stream>>>(weight, w_ih, w_hh, b_ih, b_hh,
                                                           B1hi, B2hi, bvec);
    k_cvt<<<(NN * CC) / 2048, 256, 0, stream>>>(x, hhi0, hlo0);

    unsigned short* hi_in = hhi0;  unsigned short* lo_in = hlo0;
    unsigned short* hi_out = hhi1; unsigned short* lo_out = hlo1;
    for (int i = 0; i < 3; i++) {
        float* outp = (i == 2) ? out : nullptr;
        k_fused<<<GEN_BLOCKS, 512, 0, stream>>>(hi_in, lo_in, hi_out, lo_out,
                                                rowptr, csr_src, inv_den,
                                                B1hi + (size_t)i * 65536,
                                                B2hi + (size_t)i * 32768,
                                                bvec, outp);
        unsigned short* th = hi_in; hi_in = hi_out; hi_out = th;
        unsigned short* tl = lo_in; lo_in = lo_out; lo_out = tl;
    }
}

// Round 4
// 813.829 us; speedup vs baseline: 1.4671x; 1.4671x over previous
//
#include <hip/hip_runtime.h>
#include <math.h>

#define NN 100000
#define NE 1600000
#define CC 128
#define C3 384
#define SCAN_B 256
#define SCAN_NB ((NN + SCAN_B - 1) / SCAN_B)  // 391 (also = coarse bucket count)

typedef __attribute__((ext_vector_type(4))) float f4;
typedef __attribute__((ext_vector_type(8))) short s8;

__device__ __forceinline__ float sigmoidf_(float x) { return 1.0f / (1.0f + __expf(-x)); }
__device__ __forceinline__ float tanhf_(float x) { return 2.0f / (1.0f + __expf(-2.0f * x)) - 1.0f; }

__device__ __forceinline__ short f2bf(float x) {
    unsigned u = __float_as_uint(x);
    unsigned r = (u + 0x7fffu + ((u >> 16) & 1u)) >> 16;
    return (short)r;
}
__device__ __forceinline__ float bf2f(short s) {
    return __uint_as_float(((unsigned)(unsigned short)s) << 16);
}

// ---- edge dtype: int64 => all odd int32 words zero. Computed per-block (L1-cached). ----
__device__ __forceinline__ int detect_flag(const int* e32) {
    int allz = 1;
#pragma unroll
    for (int i = 0; i < 32; i++)
        if (e32[2 * i + 1] != 0) allz = 0;
    return allz;
}

__device__ __forceinline__ int edge_val(const void* edges, int f, long long idx) {
    return f ? (int)((const long long*)edges)[idx] : ((const int*)edges)[idx];
}

__global__ void k_count(const void* __restrict__ edges, int* __restrict__ counts) {
    __shared__ int sf;
    if (threadIdx.x == 0) sf = detect_flag((const int*)edges);
    __syncthreads();
    int f = sf;
    int e = blockIdx.x * blockDim.x + threadIdx.x;
    if (e < NE) {
        int d = edge_val(edges, f, (long long)NE + e);
        atomicAdd(&counts[d], 1);
    }
}

// ---- multi-block scan ----
__global__ void k_scan1(const int* __restrict__ counts, int* __restrict__ bsum) {
    __shared__ int red[4];
    int t = threadIdx.x;
    int i = blockIdx.x * SCAN_B + t;
    int v = (i < NN) ? counts[i] : 0;
#pragma unroll
    for (int off = 32; off; off >>= 1) v += __shfl_down(v, off);
    if ((t & 63) == 0) red[t >> 6] = v;
    __syncthreads();
    if (t == 0) bsum[blockIdx.x] = red[0] + red[1] + red[2] + red[3];
}

__global__ void k_scan2(const int* __restrict__ bsum, int* __restrict__ boff,
                        int* __restrict__ coarse_cursor) {
    __shared__ int lds[512];
    int t = threadIdx.x;
    int v = (t < SCAN_NB) ? bsum[t] : 0;
    lds[t] = v;
    __syncthreads();
    for (int off = 1; off < 512; off <<= 1) {
        int u = (t >= off) ? lds[t - off] : 0;
        __syncthreads();
        lds[t] += u;
        __syncthreads();
    }
    if (t < SCAN_NB) {
        int ex = lds[t] - v;
        boff[t] = ex;
        coarse_cursor[t] = ex;
    }
}

__global__ void k_scan3(const int* __restrict__ counts, const int* __restrict__ boff,
                        int* __restrict__ rowptr, float* __restrict__ inv_denom) {
    __shared__ int lds[SCAN_B];
    int t = threadIdx.x;
    int i = blockIdx.x * SCAN_B + t;
    int v = (i < NN) ? counts[i] : 0;
    lds[t] = v;
    __syncthreads();
    for (int off = 1; off < SCAN_B; off <<= 1) {
        int u = (t >= off) ? lds[t - off] : 0;
        __syncthreads();
        lds[t] += u;
        __syncthreads();
    }
    if (i < NN) {
        rowptr[i] = boff[blockIdx.x] + lds[t] - v;
        inv_denom[i] = 1.0f / (float)((v > 1) ? v : 1);
    }
    if (i == 0) rowptr[NN] = NE;
}

// ---- CSR build phase 1: partition into coarse-bucket-grouped (src,dst) pairs ----
__global__ __launch_bounds__(1024) void k_part(const void* __restrict__ edges,
                                               int* __restrict__ coarse_cursor,
                                               uint2* __restrict__ tmp) {
    __shared__ int hist[SCAN_NB];
    __shared__ int base[SCAN_NB];
    __shared__ int sf;
    int t = threadIdx.x;
    if (t == 0) sf = detect_flag((const int*)edges);
    long long e0 = (long long)blockIdx.x * 8192;

    for (int c = t; c < SCAN_NB; c += 1024) hist[c] = 0;
    __syncthreads();
    int f = sf;

    int src[8], dst[8];
#pragma unroll
    for (int i = 0; i < 8; i++) {
        long long e = e0 + i * 1024 + t;
        if (e < NE) {
            src[i] = edge_val(edges, f, e);
            dst[i] = edge_val(edges, f, NE + e);
            atomicAdd(&hist[dst[i] >> 8], 1);
        } else {
            dst[i] = -1;
        }
    }
    __syncthreads();
    for (int c = t; c < SCAN_NB; c += 1024) {
        int h = hist[c];
        base[c] = (h > 0) ? atomicAdd(&coarse_cursor[c], h) : 0;
        hist[c] = 0;
    }
    __syncthreads();
#pragma unroll
    for (int i = 0; i < 8; i++) {
        if (dst[i] >= 0) {
            int c = dst[i] >> 8;
            int off = atomicAdd(&hist[c], 1);
            tmp[base[c] + off] = make_uint2((unsigned)src[i], (unsigned)dst[i]);
        }
    }
}

// ---- CSR build phase 2 ----
__global__ void k_fine(const uint2* __restrict__ tmp, const int* __restrict__ rowptr,
                       int* __restrict__ csr_src) {
    __shared__ int cur[256];
    int c = blockIdx.x;
    int t = threadIdx.x;
    int d = c * 256 + t;
    cur[t] = (d <= NN) ? rowptr[d < NN ? d : NN] : NE;
    __syncthreads();
    int start = rowptr[c * 256];
    int endd = (c * 256 + 256 <= NN) ? rowptr[c * 256 + 256] : NE;
    for (int p = start + t; p < endd; p += 256) {
        uint2 pr = tmp[p];
        int slot = atomicAdd(&cur[pr.y & 255], 1);
        csr_src[slot] = (int)pr.x;
    }
}

// ---- weight prep: hi-only B matrices (B bf16-quantized; ah*bl term dropped per R12) ----
__global__ void k_prep(const float* __restrict__ weight, const float* __restrict__ w_ih,
                       const float* __restrict__ w_hh, const float* __restrict__ b_ih,
                       const float* __restrict__ b_hh,
                       short* __restrict__ B1hi, short* __restrict__ B2hi,
                       float* __restrict__ bvec) {
    const int P1 = 3 * C3 * CC;
    int gid = blockIdx.x * blockDim.x + threadIdx.x;
    if (gid < P1) {
        int i = gid / (C3 * CC);
        int rem = gid % (C3 * CC);
        int j = rem / CC;
        int k = rem % CC;
        const float* Wr = weight + i * CC * CC + k * CC;
        const float* ir = w_ih + j * CC;
        float v = 0.f;
#pragma unroll 4
        for (int c = 0; c < CC; c++) v += Wr[c] * ir[c];
        short hi = f2bf(v);
        if (j < 256) B1hi[i * 65536 + j * 256 + k] = hi;
        else B2hi[i * 32768 + (j - 256) * 128 + k] = hi;
    } else if (gid < 2 * P1) {
        int g = gid - P1;
        int i = g / (C3 * CC);
        int rem = g % (C3 * CC);
        int j = rem / CC;
        int k = rem % CC;
        short hi = f2bf(w_hh[j * CC + k]);
        if (j < 256) B1hi[i * 65536 + j * 256 + 128 + k] = hi;
        else B2hi[i * 32768 + (j - 256 + 128) * 128 + k] = hi;
    } else if (gid < 2 * P1 + 512) {
        int j = gid - 2 * P1;
        float v;
        if (j < 256) v = b_ih[j] + b_hh[j];
        else if (j < 384) v = b_ih[j];
        else v = b_hh[j - 128];
        bvec[j] = v;
    }
}

// ---- x -> split-bf16 dense hhi/hlo ----
__global__ void k_cvt(const float* __restrict__ x, unsigned short* __restrict__ hhi,
                      unsigned short* __restrict__ hlo) {
    long long g = ((long long)blockIdx.x * 256 + threadIdx.x) * 8;
    float4 v0 = *(const float4*)(x + g);
    float4 v1 = *(const float4*)(x + g + 4);
    float f[8] = {v0.x, v0.y, v0.z, v0.w, v1.x, v1.y, v1.z, v1.w};
    s8 oh, ol;
#pragma unroll
    for (int q = 0; q < 8; q++) {
        short hi = f2bf(f[q]);
        oh[q] = hi;
        ol[q] = f2bf(f[q] - bf2f(hi));
    }
    *(s8*)(hhi + g) = oh;
    *(s8*)(hlo + g) = ol;
}

// ---- FUSED layer: gather+mean -> split-A x bf16-B MFMA GEMM -> GRU -> h_out / out ----
// R16: back to the best 64-node base (R0). NEW: edge-balanced gather. The block's
// whole edge span [rowptr[nb], rowptr[nb+64]) is split into 32 equal contiguous
// ranges, one per quarter-wave (every lane processes ~32 edges -> no SIMT straggler
// waste from Poisson-degree rows). Partial row sums accumulate in registers and are
// flushed run-wise via ds_add_f32 into an f32 agg[64][128] buffer ALIASED over the
// Ahi/Alo cols-0..127 LDS region (dead during gather). Mean/cvt reads agg into regs,
// barriers, then writes the MFMA layout in place. LDS total unchanged (66 KB).
__global__ __launch_bounds__(512, 4) void k_fused(
    const unsigned short* __restrict__ hhi_i, const unsigned short* __restrict__ hlo_i,
    unsigned short* __restrict__ hhi_o, unsigned short* __restrict__ hlo_o,
    const int* __restrict__ rowptr, const int* __restrict__ csr_src,
    const float* __restrict__ inv_denom,
    const short* __restrict__ B1hi, const short* __restrict__ B2hi,
    const float* __restrict__ bvec, float* __restrict__ out) {
    __shared__ short AA[32768];  // Ahi = AA[0:16384], Alo = AA[16384:32768]
    __shared__ float osum[64];
    __shared__ int rp[65];
    short* Ahi = AA;
    short* Alo = AA + 16384;
    int t = threadIdx.x;
    long long nb = (long long)blockIdx.x * 64;
    int wv = t >> 6;
    int L = t & 63;

    if (out && t < 64) osum[t] = 0.f;
    if (t < 65) {
        long long ridx = nb + t;
        rp[t] = rowptr[ridx > NN ? NN : ridx];
    }

    // zero agg: 4096 f32 in each of the two cols-0..127 regions
    {
        float* a0 = (float*)AA;            // rows 0..31
        float* a1 = (float*)(AA + 16384);  // rows 32..63
#pragma unroll
        for (int i = 0; i < 8; i++) {
            a0[t + 512 * i] = 0.f;
            a1[t + 512 * i] = 0.f;
        }
    }

    // stage h half (cols 128..255): disjoint from agg region (off in [8192,16384))
#pragma unroll
    for (int i = 0; i < 2; i++) {
        int ci = t + 512 * i;
        int rr = ci >> 4;
        int c = ci & 15;
        int c4 = 16 + c;
        long long row = nb + rr;
        if (row >= NN) row = NN - 1;
        int off = (c4 >> 2) * 2048 + (rr >> 4) * 512 + (rr & 15) * 32 + (c4 & 3) * 8;
        long long gsrc = row * CC + c * 8;
        *(s8*)&Ahi[off] = *(const s8*)(hhi_i + gsrc);
        *(s8*)&Alo[off] = *(const s8*)(hlo_i + gsrc);
    }
    __syncthreads();  // rp + agg-zero visible before gather

    // edge-balanced gather: quarter-wave qw owns contiguous edge range
    {
        int qw = t >> 4;
        int l16 = t & 15;
        int ebeg = rp[0], eend = rp[64];
        int tot = eend - ebeg;
        int per = (tot + 31) >> 5;
        int e0 = ebeg + qw * per;
        int e1 = e0 + per;
        if (e1 > eend) e1 = eend;
        if (e0 < eend) {
            // binary search: cur = row containing edge e0
            int lo2 = 0, hi2 = 64;
            while (hi2 - lo2 > 1) {
                int mid = (lo2 + hi2) >> 1;
                if (e0 >= rp[mid]) lo2 = mid;
                else hi2 = mid;
            }
            int cur = lo2;
            float acc[8] = {0, 0, 0, 0, 0, 0, 0, 0};
            auto aggrow = [&](int r) -> float* {
                return (float*)(AA + ((r >> 5) << 14)) + (r & 31) * 128 + l16 * 8;
            };
            auto adv = [&](int ei) {
                if (ei >= rp[cur + 1]) {
                    float* ap = aggrow(cur);
#pragma unroll
                    for (int k = 0; k < 8; k++) {
                        atomicAdd(&ap[k], acc[k]);
                        acc[k] = 0.f;
                    }
                    do { cur++; } while (ei >= rp[cur + 1]);
                }
            };
            int e = e0;
            for (; e + 3 < e1; e += 4) {
                int s0 = csr_src[e];
                int s1 = csr_src[e + 1];
                int s2 = csr_src[e + 2];
                int s3 = csr_src[e + 3];
                s8 v0 = ((const s8*)(hhi_i + (long long)s0 * CC))[l16];
                s8 v1 = ((const s8*)(hhi_i + (long long)s1 * CC))[l16];
                s8 v2 = ((const s8*)(hhi_i + (long long)s2 * CC))[l16];
                s8 v3 = ((const s8*)(hhi_i + (long long)s3 * CC))[l16];
                adv(e);
#pragma unroll
                for (int k = 0; k < 8; k++) acc[k] += bf2f(v0[k]);
                adv(e + 1);
#pragma unroll
                for (int k = 0; k < 8; k++) acc[k] += bf2f(v1[k]);
                adv(e + 2);
#pragma unroll
                for (int k = 0; k < 8; k++) acc[k] += bf2f(v2[k]);
                adv(e + 3);
#pragma unroll
                for (int k = 0; k < 8; k++) acc[k] += bf2f(v3[k]);
            }
            for (; e < e1; e++) {
                int s0 = csr_src[e];
                s8 v0 = ((const s8*)(hhi_i + (long long)s0 * CC))[l16];
                adv(e);
#pragma unroll
                for (int k = 0; k < 8; k++) acc[k] += bf2f(v0[k]);
            }
            // final flush
            {
                float* ap = aggrow(cur);
#pragma unroll
                for (int k = 0; k < 8; k++) atomicAdd(&ap[k], acc[k]);
            }
        }
    }
    __syncthreads();

    // mean + split-bf16 cvt: read agg to regs, barrier, overwrite region with A layout
    {
        int l16 = t & 15;
        int q = L >> 4;
        s8 vh0, vl0, vh1, vl1;
        int off0, off1;
#pragma unroll
        for (int pass = 0; pass < 2; pass++) {
            int rr = wv * 8 + pass * 4 + q;
            long long rowc = nb + rr;
            if (rowc >= NN) rowc = NN - 1;
            float inv = inv_denom[rowc];
            const float* ap = (const float*)(AA + ((rr >> 5) << 14)) + (rr & 31) * 128 + l16 * 8;
            s8 vh, vl;
#pragma unroll
            for (int k = 0; k < 8; k++) {
                float f = ap[k] * inv;
                short hi16 = f2bf(f);
                vh[k] = hi16;
                vl[k] = f2bf(f - bf2f(hi16));
            }
            int off = (l16 >> 2) * 2048 + (rr >> 4) * 512 + (rr & 15) * 32 + (l16 & 3) * 8;
            if (pass == 0) { vh0 = vh; vl0 = vl; off0 = off; }
            else { vh1 = vh; vl1 = vl; off1 = off; }
        }
        __syncthreads();  // all agg reads complete before overwrite
        *(s8*)&Ahi[off0] = vh0;
        *(s8*)&Alo[off0] = vl0;
        *(s8*)&Ahi[off1] = vh1;
        *(s8*)&Alo[off1] = vl1;
    }
    __syncthreads();

    int lm = L & 15;
    int lq = L >> 4;
    int j = wv * 16 + lm;

    f4 aR[4], aZ[4], aN[4], aH[4];
    {
        float bR = bvec[j], bZ = bvec[128 + j], bN = bvec[256 + j], bH = bvec[384 + j];
#pragma unroll
        for (int ch = 0; ch < 4; ch++) {
            aR[ch] = (f4){bR, bR, bR, bR};
            aZ[ch] = (f4){bZ, bZ, bZ, bZ};
            aN[ch] = (f4){bN, bN, bN, bN};
            aH[ch] = (f4){bH, bH, bH, bH};
        }
    }

#pragma unroll
    for (int ks = 0; ks < 8; ks++) {
        int o1 = ks * 32 + lq * 8;
        s8 bRh = *(const s8*)(B1hi + j * 256 + o1);
        s8 bZh = *(const s8*)(B1hi + (128 + j) * 256 + o1);
        int rowG = (ks < 4) ? j : (128 + j);
        int o2 = (ks & 3) * 32 + lq * 8;
        s8 bGh = *(const s8*)(B2hi + rowG * 128 + o2);
#pragma unroll
        for (int ch = 0; ch < 4; ch++) {
            int aoff = ks * 2048 + ch * 512 + lm * 32 + lq * 8;
            s8 ah = *(const s8*)&Ahi[aoff];
            s8 al = *(const s8*)&Alo[aoff];
            aR[ch] = __builtin_amdgcn_mfma_f32_16x16x32_bf16(ah, bRh, aR[ch], 0, 0, 0);
            aR[ch] = __builtin_amdgcn_mfma_f32_16x16x32_bf16(al, bRh, aR[ch], 0, 0, 0);
            aZ[ch] = __builtin_amdgcn_mfma_f32_16x16x32_bf16(ah, bZh, aZ[ch], 0, 0, 0);
            aZ[ch] = __builtin_amdgcn_mfma_f32_16x16x32_bf16(al, bZh, aZ[ch], 0, 0, 0);
            if (ks < 4) {
                aN[ch] = __builtin_amdgcn_mfma_f32_16x16x32_bf16(ah, bGh, aN[ch], 0, 0, 0);
                aN[ch] = __builtin_amdgcn_mfma_f32_16x16x32_bf16(al, bGh, aN[ch], 0, 0, 0);
            } else {
                aH[ch] = __builtin_amdgcn_mfma_f32_16x16x32_bf16(ah, bGh, aH[ch], 0, 0, 0);
                aH[ch] = __builtin_amdgcn_mfma_f32_16x16x32_bf16(al, bGh, aH[ch], 0, 0, 0);
            }
        }
    }

    // register-only GRU epilogue
    {
        int c4 = 16 + (j >> 3);
        int obase = (c4 >> 2) * 2048 + (c4 & 3) * 8 + (j & 7);
#pragma unroll
        for (int ch = 0; ch < 4; ch++) {
#pragma unroll
            for (int r = 0; r < 4; r++) {
                int node = ch * 16 + lq * 4 + r;
                int off = obase + ch * 512 + (node & 15) * 32;
                float hp = bf2f(Ahi[off]) + bf2f(Alo[off]);
                float rg = sigmoidf_(aR[ch][r]);
                float zg = sigmoidf_(aZ[ch][r]);
                float nv = tanhf_(aN[ch][r] + rg * aH[ch][r]);
                float val = (1.f - zg) * nv + zg * hp;
                long long gnode = nb + node;
                if (out) {
                    atomicAdd(&osum[node], val);
                } else if (gnode < NN) {
                    long long gd = gnode * CC + j;
                    short vh = f2bf(val);
                    hhi_o[gd] = (unsigned short)vh;
                    hlo_o[gd] = (unsigned short)f2bf(val - bf2f(vh));
                }
            }
        }
    }
    if (out) {
        __syncthreads();
        if (t < 64 && nb + t < NN)
            out[nb + t] = tanhf_(osum[t] * (1.0f / 128.0f));
    }
}

extern "C" void kernel_launch(void* const* d_in, const int* in_sizes, int n_in,
                              void* d_out, int out_size, void* d_ws, size_t ws_size,
                              hipStream_t stream) {
    const float* x = (const float*)d_in[0];
    const void* edges = d_in[1];
    const float* weight = (const float*)d_in[2];
    const float* w_ih = (const float*)d_in[3];
    const float* w_hh = (const float*)d_in[4];
    const float* b_ih = (const float*)d_in[5];
    const float* b_hh = (const float*)d_in[6];
    float* out = (float*)d_out;

    char* ws = (char*)d_ws;
    size_t off = 0;
    auto alloc = [&](size_t bytes) -> char* {
        char* p = ws + off;
        off += (bytes + 255) & ~(size_t)255;
        return p;
    };
    // total ws ~122 MB (proven-safe watermark from R4: 162.8 MB)
    int* counts = (int*)alloc((size_t)NN * 4);
    int* rowptr = (int*)alloc((size_t)(NN + 1) * 4);
    int* csr_src = (int*)alloc((size_t)NE * 4);
    float* inv_den = (float*)alloc((size_t)NN * 4);
    int* bsum = (int*)alloc((size_t)SCAN_NB * 4);
    int* boff = (int*)alloc((size_t)SCAN_NB * 4);
    int* coarse_cursor = (int*)alloc((size_t)SCAN_NB * 4);
    uint2* tmp = (uint2*)alloc((size_t)NE * 8);
    short* B1hi = (short*)alloc((size_t)3 * 65536 * 2);
    short* B2hi = (short*)alloc((size_t)3 * 32768 * 2);
    float* bvec = (float*)alloc(512 * 4);
    unsigned short* hhi0 = (unsigned short*)alloc((size_t)NN * CC * 2);
    unsigned short* hlo0 = (unsigned short*)alloc((size_t)NN * CC * 2);
    unsigned short* hhi1 = (unsigned short*)alloc((size_t)NN * CC * 2);
    unsigned short* hlo1 = (unsigned short*)alloc((size_t)NN * CC * 2);

    hipMemsetAsync(counts, 0, (size_t)NN * 4, stream);

    k_count<<<(NE + 255) / 256, 256, 0, stream>>>(edges, counts);
    k_scan1<<<SCAN_NB, SCAN_B, 0, stream>>>(counts, bsum);
    k_scan2<<<1, 512, 0, stream>>>(bsum, boff, coarse_cursor);
    k_scan3<<<SCAN_NB, SCAN_B, 0, stream>>>(counts, boff, rowptr, inv_den);
    k_part<<<(NE + 8191) / 8192, 1024, 0, stream>>>(edges, coarse_cursor, tmp);
    k_fine<<<SCAN_NB, 256, 0, stream>>>(tmp, rowptr, csr_src);
    int prep_threads = 2 * 3 * C3 * CC + 512;
    k_prep<<<(prep_threads + 255) / 256, 256, 0, stream>>>(weight, w_ih, w_hh, b_ih, b_hh,
                                                           B1hi, B2hi, bvec);
    k_cvt<<<(NN * CC) / 2048, 256, 0, stream>>>(x, hhi0, hlo0);

    const int blocks = (NN + 63) / 64;  // 1563
    unsigned short* hi_in = hhi0;  unsigned short* lo_in = hlo0;
    unsigned short* hi_out = hhi1; unsigned short* lo_out = hlo1;
    for (int i = 0; i < 3; i++) {
        float* outp = (i == 2) ? out : nullptr;
        k_fused<<<blocks, 512, 0, stream>>>(hi_in, lo_in, hi_out, lo_out,
                                            rowptr, csr_src, inv_den,
                                            B1hi + (size_t)i * 65536,
                                            B2hi + (size_t)i * 32768,
                                            bvec, outp);
        unsigned short* th = hi_in; hi_in = hi_out; hi_out = th;
        unsigned short* tl = lo_in; lo_in = lo_out; lo_out = tl;
    }
}

// Round 5
// 626.736 us; speedup vs baseline: 1.9050x; 1.2985x over previous
//
#include <hip/hip_runtime.h>
#include <math.h>

#define NN 100000
#define NE 1600000
#define CC 128
#define C3 384
#define SCAN_B 256
#define SCAN_NB ((NN + SCAN_B - 1) / SCAN_B)  // 391 (also = coarse bucket count)

typedef __attribute__((ext_vector_type(4))) float f4;
typedef __attribute__((ext_vector_type(8))) short s8;

__device__ __forceinline__ float sigmoidf_(float x) { return 1.0f / (1.0f + __expf(-x)); }
__device__ __forceinline__ float tanhf_(float x) { return 2.0f / (1.0f + __expf(-2.0f * x)) - 1.0f; }

__device__ __forceinline__ short f2bf(float x) {
    unsigned u = __float_as_uint(x);
    unsigned r = (u + 0x7fffu + ((u >> 16) & 1u)) >> 16;
    return (short)r;
}
__device__ __forceinline__ float bf2f(short s) {
    return __uint_as_float(((unsigned)(unsigned short)s) << 16);
}

// ---- edge dtype: int64 => all odd int32 words zero. Computed per-block (L1-cached). ----
__device__ __forceinline__ int detect_flag(const int* e32) {
    int allz = 1;
#pragma unroll
    for (int i = 0; i < 32; i++)
        if (e32[2 * i + 1] != 0) allz = 0;
    return allz;
}

__device__ __forceinline__ int edge_val(const void* edges, int f, long long idx) {
    return f ? (int)((const long long*)edges)[idx] : ((const int*)edges)[idx];
}

__global__ void k_count(const void* __restrict__ edges, int* __restrict__ counts) {
    __shared__ int sf;
    if (threadIdx.x == 0) sf = detect_flag((const int*)edges);
    __syncthreads();
    int f = sf;
    int e = blockIdx.x * blockDim.x + threadIdx.x;
    if (e < NE) {
        int d = edge_val(edges, f, (long long)NE + e);
        atomicAdd(&counts[d], 1);
    }
}

// ---- multi-block scan ----
__global__ void k_scan1(const int* __restrict__ counts, int* __restrict__ bsum) {
    __shared__ int red[4];
    int t = threadIdx.x;
    int i = blockIdx.x * SCAN_B + t;
    int v = (i < NN) ? counts[i] : 0;
#pragma unroll
    for (int off = 32; off; off >>= 1) v += __shfl_down(v, off);
    if ((t & 63) == 0) red[t >> 6] = v;
    __syncthreads();
    if (t == 0) bsum[blockIdx.x] = red[0] + red[1] + red[2] + red[3];
}

__global__ void k_scan2(const int* __restrict__ bsum, int* __restrict__ boff,
                        int* __restrict__ coarse_cursor) {
    __shared__ int lds[512];
    int t = threadIdx.x;
    int v = (t < SCAN_NB) ? bsum[t] : 0;
    lds[t] = v;
    __syncthreads();
    for (int off = 1; off < 512; off <<= 1) {
        int u = (t >= off) ? lds[t - off] : 0;
        __syncthreads();
        lds[t] += u;
        __syncthreads();
    }
    if (t < SCAN_NB) {
        int ex = lds[t] - v;
        boff[t] = ex;
        coarse_cursor[t] = ex;
    }
}

__global__ void k_scan3(const int* __restrict__ counts, const int* __restrict__ boff,
                        int* __restrict__ rowptr, float* __restrict__ inv_denom) {
    __shared__ int lds[SCAN_B];
    int t = threadIdx.x;
    int i = blockIdx.x * SCAN_B + t;
    int v = (i < NN) ? counts[i] : 0;
    lds[t] = v;
    __syncthreads();
    for (int off = 1; off < SCAN_B; off <<= 1) {
        int u = (t >= off) ? lds[t - off] : 0;
        __syncthreads();
        lds[t] += u;
        __syncthreads();
    }
    if (i < NN) {
        rowptr[i] = boff[blockIdx.x] + lds[t] - v;
        inv_denom[i] = 1.0f / (float)((v > 1) ? v : 1);
    }
    if (i == 0) rowptr[NN] = NE;
}

// ---- CSR build phase 1: partition into coarse-bucket-grouped (src,dst) pairs ----
__global__ __launch_bounds__(1024) void k_part(const void* __restrict__ edges,
                                               int* __restrict__ coarse_cursor,
                                               uint2* __restrict__ tmp) {
    __shared__ int hist[SCAN_NB];
    __shared__ int base[SCAN_NB];
    __shared__ int sf;
    int t = threadIdx.x;
    if (t == 0) sf = detect_flag((const int*)edges);
    long long e0 = (long long)blockIdx.x * 8192;

    for (int c = t; c < SCAN_NB; c += 1024) hist[c] = 0;
    __syncthreads();
    int f = sf;

    int src[8], dst[8];
#pragma unroll
    for (int i = 0; i < 8; i++) {
        long long e = e0 + i * 1024 + t;
        if (e < NE) {
            src[i] = edge_val(edges, f, e);
            dst[i] = edge_val(edges, f, NE + e);
            atomicAdd(&hist[dst[i] >> 8], 1);
        } else {
            dst[i] = -1;
        }
    }
    __syncthreads();
    for (int c = t; c < SCAN_NB; c += 1024) {
        int h = hist[c];
        base[c] = (h > 0) ? atomicAdd(&coarse_cursor[c], h) : 0;
        hist[c] = 0;
    }
    __syncthreads();
#pragma unroll
    for (int i = 0; i < 8; i++) {
        if (dst[i] >= 0) {
            int c = dst[i] >> 8;
            int off = atomicAdd(&hist[c], 1);
            tmp[base[c] + off] = make_uint2((unsigned)src[i], (unsigned)dst[i]);
        }
    }
}

// ---- CSR build phase 2 ----
__global__ void k_fine(const uint2* __restrict__ tmp, const int* __restrict__ rowptr,
                       int* __restrict__ csr_src) {
    __shared__ int cur[256];
    int c = blockIdx.x;
    int t = threadIdx.x;
    int d = c * 256 + t;
    cur[t] = (d <= NN) ? rowptr[d < NN ? d : NN] : NE;
    __syncthreads();
    int start = rowptr[c * 256];
    int endd = (c * 256 + 256 <= NN) ? rowptr[c * 256 + 256] : NE;
    for (int p = start + t; p < endd; p += 256) {
        uint2 pr = tmp[p];
        int slot = atomicAdd(&cur[pr.y & 255], 1);
        csr_src[slot] = (int)pr.x;
    }
}

// ---- weight prep: hi-only B matrices (B bf16-quantized; ah*bl term dropped per R12) ----
__global__ void k_prep(const float* __restrict__ weight, const float* __restrict__ w_ih,
                       const float* __restrict__ w_hh, const float* __restrict__ b_ih,
                       const float* __restrict__ b_hh,
                       short* __restrict__ B1hi, short* __restrict__ B2hi,
                       float* __restrict__ bvec) {
    const int P1 = 3 * C3 * CC;
    int gid = blockIdx.x * blockDim.x + threadIdx.x;
    if (gid < P1) {
        int i = gid / (C3 * CC);
        int rem = gid % (C3 * CC);
        int j = rem / CC;
        int k = rem % CC;
        const float* Wr = weight + i * CC * CC + k * CC;
        const float* ir = w_ih + j * CC;
        float v = 0.f;
#pragma unroll 4
        for (int c = 0; c < CC; c++) v += Wr[c] * ir[c];
        short hi = f2bf(v);
        if (j < 256) B1hi[i * 65536 + j * 256 + k] = hi;
        else B2hi[i * 32768 + (j - 256) * 128 + k] = hi;
    } else if (gid < 2 * P1) {
        int g = gid - P1;
        int i = g / (C3 * CC);
        int rem = g % (C3 * CC);
        int j = rem / CC;
        int k = rem % CC;
        short hi = f2bf(w_hh[j * CC + k]);
        if (j < 256) B1hi[i * 65536 + j * 256 + 128 + k] = hi;
        else B2hi[i * 32768 + (j - 256 + 128) * 128 + k] = hi;
    } else if (gid < 2 * P1 + 512) {
        int j = gid - 2 * P1;
        float v;
        if (j < 256) v = b_ih[j] + b_hh[j];
        else if (j < 384) v = b_ih[j];
        else v = b_hh[j - 128];
        bvec[j] = v;
    }
}

// ---- x -> split-bf16 dense hhi/hlo ----
__global__ void k_cvt(const float* __restrict__ x, unsigned short* __restrict__ hhi,
                      unsigned short* __restrict__ hlo) {
    long long g = ((long long)blockIdx.x * 256 + threadIdx.x) * 8;
    float4 v0 = *(const float4*)(x + g);
    float4 v1 = *(const float4*)(x + g + 4);
    float f[8] = {v0.x, v0.y, v0.z, v0.w, v1.x, v1.y, v1.z, v1.w};
    s8 oh, ol;
#pragma unroll
    for (int q = 0; q < 8; q++) {
        short hi = f2bf(f[q]);
        oh[q] = hi;
        ol[q] = f2bf(f[q] - bf2f(hi));
    }
    *(s8*)(hhi + g) = oh;
    *(s8*)(hlo + g) = ol;
}

// ---- FUSED layer: gather+mean -> split-A x bf16-B MFMA GEMM -> GRU -> h_out / out ----
// R17 = R0 champion base (64 nodes/block, 512 thr, launch_bounds(512,4), 128-VGPR
// budget) + deep-ILP gather: 8 row-loads in flight per quarter-wave AND the next 8
// csr indices prefetched while current rows are outstanding (removes the csr->row
// serial round-trip from the critical chain). R2's ILP-8 was void: launch_bounds
// (512,8) capped VGPR at 32 so loads serialized; here the budget is 128.
// Accumulation order is BIT-IDENTICAL to R0 (two consecutive ILP-4 groups).
__global__ __launch_bounds__(512, 4) void k_fused(
    const unsigned short* __restrict__ hhi_i, const unsigned short* __restrict__ hlo_i,
    unsigned short* __restrict__ hhi_o, unsigned short* __restrict__ hlo_o,
    const int* __restrict__ rowptr, const int* __restrict__ csr_src,
    const float* __restrict__ inv_denom,
    const short* __restrict__ B1hi, const short* __restrict__ B2hi,
    const float* __restrict__ bvec, float* __restrict__ out) {
    __shared__ short Ahi[16384];
    __shared__ short Alo[16384];
    __shared__ float osum[64];
    int t = threadIdx.x;
    long long nb = (long long)blockIdx.x * 64;
    int wv = t >> 6;
    int L = t & 63;

    if (out && t < 64) osum[t] = 0.f;

    // stage h half (cols 128..255): branch-free s8 copies
#pragma unroll
    for (int i = 0; i < 2; i++) {
        int ci = t + 512 * i;
        int rr = ci >> 4;
        int c = ci & 15;
        int c4 = 16 + c;
        long long row = nb + rr;
        if (row >= NN) row = NN - 1;
        int off = (c4 >> 2) * 2048 + (rr >> 4) * 512 + (rr & 15) * 32 + (c4 & 3) * 8;
        long long gsrc = row * CC + c * 8;
        *(s8*)&Ahi[off] = *(const s8*)(hhi_i + gsrc);
        *(s8*)&Alo[off] = *(const s8*)(hlo_i + gsrc);
    }

    // gather + mean into A cols 0..127: quarter-wave per node, ILP-8 + csr prefetch
    {
        int q = L >> 4;
        int l16 = L & 15;
#pragma unroll
        for (int pass = 0; pass < 2; pass++) {
            int rr = wv * 8 + pass * 4 + q;
            long long rowc = nb + rr;
            if (rowc >= NN) rowc = NN - 1;
            int lo = rowptr[rowc], hi = rowptr[rowc + 1];
            float acc0[8] = {0, 0, 0, 0, 0, 0, 0, 0};
            float acc1[8] = {0, 0, 0, 0, 0, 0, 0, 0};
            int e = lo;
            if (e + 7 < hi) {
                int s0 = csr_src[e];
                int s1 = csr_src[e + 1];
                int s2 = csr_src[e + 2];
                int s3 = csr_src[e + 3];
                int s4 = csr_src[e + 4];
                int s5 = csr_src[e + 5];
                int s6 = csr_src[e + 6];
                int s7 = csr_src[e + 7];
                while (true) {
                    // issue 8 independent row loads
                    s8 v0 = ((const s8*)(hhi_i + (long long)s0 * CC))[l16];
                    s8 v1 = ((const s8*)(hhi_i + (long long)s1 * CC))[l16];
                    s8 v2 = ((const s8*)(hhi_i + (long long)s2 * CC))[l16];
                    s8 v3 = ((const s8*)(hhi_i + (long long)s3 * CC))[l16];
                    s8 v4 = ((const s8*)(hhi_i + (long long)s4 * CC))[l16];
                    s8 v5 = ((const s8*)(hhi_i + (long long)s5 * CC))[l16];
                    s8 v6 = ((const s8*)(hhi_i + (long long)s6 * CC))[l16];
                    s8 v7 = ((const s8*)(hhi_i + (long long)s7 * CC))[l16];
                    // prefetch next iteration's csr indices (independent of accs)
                    bool more = (e + 15 < hi);
                    int n0, n1, n2, n3, n4, n5, n6, n7;
                    if (more) {
                        n0 = csr_src[e + 8];
                        n1 = csr_src[e + 9];
                        n2 = csr_src[e + 10];
                        n3 = csr_src[e + 11];
                        n4 = csr_src[e + 12];
                        n5 = csr_src[e + 13];
                        n6 = csr_src[e + 14];
                        n7 = csr_src[e + 15];
                    }
                    // accumulate: exactly two R0 ILP-4 groups (bit-identical order)
#pragma unroll
                    for (int k = 0; k < 8; k++) {
                        acc0[k] += bf2f(v0[k]) + bf2f(v2[k]);
                        acc1[k] += bf2f(v1[k]) + bf2f(v3[k]);
                    }
#pragma unroll
                    for (int k = 0; k < 8; k++) {
                        acc0[k] += bf2f(v4[k]) + bf2f(v6[k]);
                        acc1[k] += bf2f(v5[k]) + bf2f(v7[k]);
                    }
                    e += 8;
                    if (!more) break;
                    s0 = n0; s1 = n1; s2 = n2; s3 = n3;
                    s4 = n4; s5 = n5; s6 = n6; s7 = n7;
                }
            }
            for (; e + 3 < hi; e += 4) {
                int s0 = csr_src[e];
                int s1 = csr_src[e + 1];
                int s2 = csr_src[e + 2];
                int s3 = csr_src[e + 3];
                s8 v0 = ((const s8*)(hhi_i + (long long)s0 * CC))[l16];
                s8 v1 = ((const s8*)(hhi_i + (long long)s1 * CC))[l16];
                s8 v2 = ((const s8*)(hhi_i + (long long)s2 * CC))[l16];
                s8 v3 = ((const s8*)(hhi_i + (long long)s3 * CC))[l16];
#pragma unroll
                for (int k = 0; k < 8; k++) {
                    acc0[k] += bf2f(v0[k]) + bf2f(v2[k]);
                    acc1[k] += bf2f(v1[k]) + bf2f(v3[k]);
                }
            }
            for (; e + 1 < hi; e += 2) {
                int s0 = csr_src[e];
                int s1 = csr_src[e + 1];
                s8 v0 = ((const s8*)(hhi_i + (long long)s0 * CC))[l16];
                s8 v1 = ((const s8*)(hhi_i + (long long)s1 * CC))[l16];
#pragma unroll
                for (int k = 0; k < 8; k++) {
                    acc0[k] += bf2f(v0[k]);
                    acc1[k] += bf2f(v1[k]);
                }
            }
            if (e < hi) {
                int s0 = csr_src[e];
                s8 v0 = ((const s8*)(hhi_i + (long long)s0 * CC))[l16];
#pragma unroll
                for (int k = 0; k < 8; k++) acc0[k] += bf2f(v0[k]);
            }
            float inv = inv_denom[rowc];
            s8 vh, vl;
#pragma unroll
            for (int k = 0; k < 8; k++) {
                float f = (acc0[k] + acc1[k]) * inv;
                short hi16 = f2bf(f);
                vh[k] = hi16;
                vl[k] = f2bf(f - bf2f(hi16));
            }
            int off = (l16 >> 2) * 2048 + (rr >> 4) * 512 + (rr & 15) * 32 + (l16 & 3) * 8;
            *(s8*)&Ahi[off] = vh;
            *(s8*)&Alo[off] = vl;
        }
    }
    __syncthreads();

    int lm = L & 15;
    int lq = L >> 4;
    int j = wv * 16 + lm;

    f4 aR[4], aZ[4], aN[4], aH[4];
    {
        float bR = bvec[j], bZ = bvec[128 + j], bN = bvec[256 + j], bH = bvec[384 + j];
#pragma unroll
        for (int ch = 0; ch < 4; ch++) {
            aR[ch] = (f4){bR, bR, bR, bR};
            aZ[ch] = (f4){bZ, bZ, bZ, bZ};
            aN[ch] = (f4){bN, bN, bN, bN};
            aH[ch] = (f4){bH, bH, bH, bH};
        }
    }

#pragma unroll
    for (int ks = 0; ks < 8; ks++) {
        int o1 = ks * 32 + lq * 8;
        s8 bRh = *(const s8*)(B1hi + j * 256 + o1);
        s8 bZh = *(const s8*)(B1hi + (128 + j) * 256 + o1);
        int rowG = (ks < 4) ? j : (128 + j);
        int o2 = (ks & 3) * 32 + lq * 8;
        s8 bGh = *(const s8*)(B2hi + rowG * 128 + o2);
#pragma unroll
        for (int ch = 0; ch < 4; ch++) {
            int aoff = ks * 2048 + ch * 512 + lm * 32 + lq * 8;
            s8 ah = *(const s8*)&Ahi[aoff];
            s8 al = *(const s8*)&Alo[aoff];
            aR[ch] = __builtin_amdgcn_mfma_f32_16x16x32_bf16(ah, bRh, aR[ch], 0, 0, 0);
            aR[ch] = __builtin_amdgcn_mfma_f32_16x16x32_bf16(al, bRh, aR[ch], 0, 0, 0);
            aZ[ch] = __builtin_amdgcn_mfma_f32_16x16x32_bf16(ah, bZh, aZ[ch], 0, 0, 0);
            aZ[ch] = __builtin_amdgcn_mfma_f32_16x16x32_bf16(al, bZh, aZ[ch], 0, 0, 0);
            if (ks < 4) {
                aN[ch] = __builtin_amdgcn_mfma_f32_16x16x32_bf16(ah, bGh, aN[ch], 0, 0, 0);
                aN[ch] = __builtin_amdgcn_mfma_f32_16x16x32_bf16(al, bGh, aN[ch], 0, 0, 0);
            } else {
                aH[ch] = __builtin_amdgcn_mfma_f32_16x16x32_bf16(ah, bGh, aH[ch], 0, 0, 0);
                aH[ch] = __builtin_amdgcn_mfma_f32_16x16x32_bf16(al, bGh, aH[ch], 0, 0, 0);
            }
        }
    }

    // register-only GRU epilogue
    {
        int c4 = 16 + (j >> 3);
        int obase = (c4 >> 2) * 2048 + (c4 & 3) * 8 + (j & 7);
#pragma unroll
        for (int ch = 0; ch < 4; ch++) {
#pragma unroll
            for (int r = 0; r < 4; r++) {
                int node = ch * 16 + lq * 4 + r;
                int off = obase + ch * 512 + (node & 15) * 32;
                float hp = bf2f(Ahi[off]) + bf2f(Alo[off]);
                float rg = sigmoidf_(aR[ch][r]);
                float zg = sigmoidf_(aZ[ch][r]);
                float nv = tanhf_(aN[ch][r] + rg * aH[ch][r]);
                float val = (1.f - zg) * nv + zg * hp;
                long long gnode = nb + node;
                if (out) {
                    atomicAdd(&osum[node], val);
                } else if (gnode < NN) {
                    long long gd = gnode * CC + j;
                    short vh = f2bf(val);
                    hhi_o[gd] = (unsigned short)vh;
                    hlo_o[gd] = (unsigned short)f2bf(val - bf2f(vh));
                }
            }
        }
    }
    if (out) {
        __syncthreads();
        if (t < 64 && nb + t < NN)
            out[nb + t] = tanhf_(osum[t] * (1.0f / 128.0f));
    }
}

extern "C" void kernel_launch(void* const* d_in, const int* in_sizes, int n_in,
                              void* d_out, int out_size, void* d_ws, size_t ws_size,
                              hipStream_t stream) {
    const float* x = (const float*)d_in[0];
    const void* edges = d_in[1];
    const float* weight = (const float*)d_in[2];
    const float* w_ih = (const float*)d_in[3];
    const float* w_hh = (const float*)d_in[4];
    const float* b_ih = (const float*)d_in[5];
    const float* b_hh = (const float*)d_in[6];
    float* out = (float*)d_out;

    char* ws = (char*)d_ws;
    size_t off = 0;
    auto alloc = [&](size_t bytes) -> char* {
        char* p = ws + off;
        off += (bytes + 255) & ~(size_t)255;
        return p;
    };
    // total ws ~122 MB (proven-safe watermark from R4: 162.8 MB)
    int* counts = (int*)alloc((size_t)NN * 4);
    int* rowptr = (int*)alloc((size_t)(NN + 1) * 4);
    int* csr_src = (int*)alloc((size_t)NE * 4);
    float* inv_den = (float*)alloc((size_t)NN * 4);
    int* bsum = (int*)alloc((size_t)SCAN_NB * 4);
    int* boff = (int*)alloc((size_t)SCAN_NB * 4);
    int* coarse_cursor = (int*)alloc((size_t)SCAN_NB * 4);
    uint2* tmp = (uint2*)alloc((size_t)NE * 8);
    short* B1hi = (short*)alloc((size_t)3 * 65536 * 2);
    short* B2hi = (short*)alloc((size_t)3 * 32768 * 2);
    float* bvec = (float*)alloc(512 * 4);
    unsigned short* hhi0 = (unsigned short*)alloc((size_t)NN * CC * 2);
    unsigned short* hlo0 = (unsigned short*)alloc((size_t)NN * CC * 2);
    unsigned short* hhi1 = (unsigned short*)alloc((size_t)NN * CC * 2);
    unsigned short* hlo1 = (unsigned short*)alloc((size_t)NN * CC * 2);

    hipMemsetAsync(counts, 0, (size_t)NN * 4, stream);

    k_count<<<(NE + 255) / 256, 256, 0, stream>>>(edges, counts);
    k_scan1<<<SCAN_NB, SCAN_B, 0, stream>>>(counts, bsum);
    k_scan2<<<1, 512, 0, stream>>>(bsum, boff, coarse_cursor);
    k_scan3<<<SCAN_NB, SCAN_B, 0, stream>>>(counts, boff, rowptr, inv_den);
    k_part<<<(NE + 8191) / 8192, 1024, 0, stream>>>(edges, coarse_cursor, tmp);
    k_fine<<<SCAN_NB, 256, 0, stream>>>(tmp, rowptr, csr_src);
    int prep_threads = 2 * 3 * C3 * CC + 512;
    k_prep<<<(prep_threads + 255) / 256, 256, 0, stream>>>(weight, w_ih, w_hh, b_ih, b_hh,
                                                           B1hi, B2hi, bvec);
    k_cvt<<<(NN * CC) / 2048, 256, 0, stream>>>(x, hhi0, hlo0);

    const int blocks = (NN + 63) / 64;  // 1563
    unsigned short* hi_in = hhi0;  unsigned short* lo_in = hlo0;
    unsigned short* hi_out = hhi1; unsigned short* lo_out = hlo1;
    for (int i = 0; i < 3; i++) {
        float* outp = (i == 2) ? out : nullptr;
        k_fused<<<blocks, 512, 0, stream>>>(hi_in, lo_in, hi_out, lo_out,
                                            rowptr, csr_src, inv_den,
                                            B1hi + (size_t)i * 65536,
                                            B2hi + (size_t)i * 32768,
                                            bvec, outp);
        unsigned short* th = hi_in; hi_in = hi_out; hi_out = th;
        unsigned short* tl = lo_in; lo_in = lo_out; lo_out = tl;
    }
}